// Round 1
// baseline (281.905 us; speedup 1.0000x reference)
//
#include <hip/hip_runtime.h>
#include <math.h>

// GAT forward: B=32 N=256 F=300(pad 320) O=256 H=8 OUT=512
// Pipeline: prep(x->f16, W->f16 transposed) -> G1 -> e-dots -> Attn1 -> G2 -> e-dots2 -> Attn2

typedef _Float16 f16;
typedef __attribute__((ext_vector_type(8))) _Float16 f16x8;
typedef __attribute__((ext_vector_type(4))) _Float16 f16x4;
typedef __attribute__((ext_vector_type(4))) float f32x4;

#define NEGBIG -9.0e15f

__device__ __forceinline__ void async16(const void* g, void* lds) {
  // 16B per lane, LDS dest = wave-uniform base + lane*16 (m97/m104 semantics)
  __builtin_amdgcn_global_load_lds(
      (const __attribute__((address_space(1))) void*)g,
      (__attribute__((address_space(3))) void*)lds, 16, 0, 0);
}

// ---------------- prep kernels ----------------
__global__ void k_prep_x(const int* __restrict__ fea, const float* __restrict__ embed,
                         f16* __restrict__ x16) {
  int row = blockIdx.x;          // 8192 = b*256+n
  int t = threadIdx.x;           // 320
  int tok = fea[row];
  float v = (t < 300) ? embed[tok * 300 + t] : 0.f;
  x16[(size_t)row * 320 + t] = (f16)v;
}

__global__ void k_prep_wc(const float* __restrict__ W, f16* __restrict__ WcT) {
  int gc = blockIdx.x;           // 2048 = h*256+o
  int t = threadIdx.x;           // 320
  int h = gc >> 8, o = gc & 255;
  float v = (t < 300) ? W[((size_t)h * 300 + t) * 256 + o] : 0.f;
  WcT[(size_t)gc * 320 + t] = (f16)v;
}

__global__ void k_prep_wo(const float* __restrict__ W, f16* __restrict__ WoT) {
  int o2 = blockIdx.x;           // 512
  int t = threadIdx.x;           // 256
  for (int k = t; k < 2048; k += 256)
    WoT[(size_t)o2 * 2048 + k] = (f16)W[(size_t)k * 512 + o2];
}

// ---------------- GEMM: C^T = (A @ B^T)^T stored as [b][col][n] f16 ----------------
// A: MxK row-major f16 (M=8192), BT: NCOLSxK row-major f16. Tile 128x128, BK=32.
template <int KDIM, int NCOLS>
__global__ __launch_bounds__(256, 2) void k_gemm(const f16* __restrict__ A,
                                                 const f16* __restrict__ BT,
                                                 f16* __restrict__ outT) {
  __shared__ f16 As[128 * 32];
  __shared__ f16 Bs[128 * 32];
  const int bx = blockIdx.x, by = blockIdx.y;
  const int tid = threadIdx.x;
  const int wave = tid >> 6, lane = tid & 63;
  const int wm = wave >> 1, wn = wave & 1;
  const int lrow = lane & 15, quad = lane >> 4;
  const int srow = lane >> 2;           // staging: 16 rows per inst
  const int scol = (lane & 3) * 8;      // f16 offset within 32-wide row

  f32x4 acc[4][4] = {};
  const f16* Ag = A + (size_t)by * 128 * KDIM;
  const f16* Bg = BT + (size_t)bx * 128 * KDIM;

  for (int k0 = 0; k0 < KDIM; k0 += 32) {
    __syncthreads();
#pragma unroll
    for (int j = 0; j < 2; ++j) {
      const int r0 = wave * 32 + j * 16;
      async16(Ag + (size_t)(r0 + srow) * KDIM + k0 + scol, &As[r0 * 32]);
      async16(Bg + (size_t)(r0 + srow) * KDIM + k0 + scol, &Bs[r0 * 32]);
    }
    __syncthreads();
    f16x8 af[4], bf[4];
#pragma unroll
    for (int t = 0; t < 4; ++t) {
      af[t] = *(const f16x8*)&As[(wm * 64 + t * 16 + lrow) * 32 + quad * 8];
      bf[t] = *(const f16x8*)&Bs[(wn * 64 + t * 16 + lrow) * 32 + quad * 8];
    }
#pragma unroll
    for (int mt = 0; mt < 4; ++mt)
#pragma unroll
      for (int nt = 0; nt < 4; ++nt)
        acc[mt][nt] = __builtin_amdgcn_mfma_f32_16x16x32_f16(af[mt], bf[nt], acc[mt][nt], 0, 0, 0);
  }

  // D[row=quad*4+r][col=lane&15]; store transposed: outT[(b*NCOLS+gc)*256 + n]
  const int b = (by * 128) >> 8;
  const int nbase0 = (by * 128) & 255;
#pragma unroll
  for (int mt = 0; mt < 4; ++mt) {
    const int nb = nbase0 + wm * 64 + mt * 16 + quad * 4;
#pragma unroll
    for (int nt = 0; nt < 4; ++nt) {
      const int gc = bx * 128 + wn * 64 + nt * 16 + lrow;
      f16x4 v;
#pragma unroll
      for (int r = 0; r < 4; ++r) v[r] = (f16)acc[mt][nt][r];
      *(f16x4*)&outT[((size_t)b * NCOLS + gc) * 256 + nb] = v;
    }
  }
}

// ---------------- e1/e2 dot kernels ----------------
__global__ void k_edots(const f16* __restrict__ WhT, const float* __restrict__ a_heads,
                        float* __restrict__ e1, float* __restrict__ e2) {
  int bh = blockIdx.x;           // 256 = b*8+h
  int h = bh & 7;
  int n = threadIdx.x;           // 256
  const f16* base = WhT + (size_t)bh * 65536 + n;
  float s1 = 0.f, s2 = 0.f;
  for (int o = 0; o < 256; ++o) {
    float w = (float)base[(size_t)o * 256];
    s1 += w * a_heads[h * 512 + o];
    s2 += w * a_heads[h * 512 + 256 + o];
  }
  e1[bh * 256 + n] = s1;
  e2[bh * 256 + n] = s2;
}

__global__ void k_edots2(const f16* __restrict__ Wh2T, const float* __restrict__ a_out,
                         float* __restrict__ e1, float* __restrict__ e2) {
  int b = blockIdx.x;            // 32
  int n = threadIdx.x;           // 256
  const f16* base = Wh2T + (size_t)b * 512 * 256 + n;
  float s1 = 0.f, s2 = 0.f;
  for (int o = 0; o < 512; ++o) {
    float w = (float)base[(size_t)o * 256];
    s1 += w * a_out[o];
    s2 += w * a_out[512 + o];
  }
  e1[b * 256 + n] = s1;
  e2[b * 256 + n] = s2;
}

// ---------------- fused attention layer 1 ----------------
// block = (nt in 4, h in 8, b in 32), 256 thr. 64 rows x 256 cols of head output.
__global__ __launch_bounds__(256, 2) void k_attn1(
    const f16* __restrict__ WhT, const float* __restrict__ e1g, const float* __restrict__ e2g,
    const int* __restrict__ adj, const float* __restrict__ npm, f16* __restrict__ h1) {
  int nt = blockIdx.x, h = blockIdx.y, b = blockIdx.z;
  int bh = b * 8 + h;
  int n0 = nt * 64;
  __shared__ f16 P[64 * 256];     // unnormalized exp, f16
  __shared__ f16 Bs[256 * 32];    // Wh chunk [o][m]
  __shared__ float e2s[256];
  __shared__ float red[256];
  __shared__ float rowsum[64];
  int tid = threadIdx.x;
  e2s[tid] = e2g[bh * 256 + tid];
  __syncthreads();
  int row = tid >> 2, seg = tid & 3;
  float er = e1g[bh * 256 + n0 + row];
  const int* adjrow = adj + ((size_t)(b * 256 + n0 + row)) * 256 + seg * 64;
  float mx = -3.0e38f;
  for (int j = 0; j < 64; ++j) {
    float v = er + e2s[seg * 64 + j];
    v = v > 0.f ? v : 0.2f * v;
    if (adjrow[j] == 0) v = NEGBIG;
    mx = fmaxf(mx, v);
  }
  red[tid] = mx;
  __syncthreads();
  mx = fmaxf(fmaxf(red[row * 4 + 0], red[row * 4 + 1]), fmaxf(red[row * 4 + 2], red[row * 4 + 3]));
  float sm = 0.f;
  for (int j = 0; j < 64; ++j) {
    float v = er + e2s[seg * 64 + j];
    v = v > 0.f ? v : 0.2f * v;
    if (adjrow[j] == 0) v = NEGBIG;
    float p = expf(v - mx);
    sm += p;
    P[row * 256 + seg * 64 + j] = (f16)p;
  }
  __syncthreads();
  red[tid] = sm;
  __syncthreads();
  if (seg == 0)
    rowsum[row] = red[row * 4] + red[row * 4 + 1] + red[row * 4 + 2] + red[row * 4 + 3];

  // PV: out(64x256) = P(64x256) @ Wh[b,h](256x256); B from WhT[b][h*256+o][m]
  int wave = tid >> 6, lane = tid & 63;
  int wm = wave >> 1, wn = wave & 1;
  int lrow = lane & 15, quad = lane >> 4;
  f32x4 acc[2][8] = {};
  const f16* Bg = WhT + (size_t)bh * 65536;
  for (int k0 = 0; k0 < 256; k0 += 32) {
    __syncthreads();
#pragma unroll
    for (int j = 0; j < 4; ++j) {
      const int r0 = wave * 64 + j * 16;
      async16(Bg + (size_t)(r0 + (lane >> 2)) * 256 + k0 + (lane & 3) * 8, &Bs[r0 * 32]);
    }
    __syncthreads();
    f16x8 a0 = *(const f16x8*)&P[(wm * 32 + lrow) * 256 + k0 + quad * 8];
    f16x8 a1 = *(const f16x8*)&P[(wm * 32 + 16 + lrow) * 256 + k0 + quad * 8];
#pragma unroll
    for (int ot = 0; ot < 8; ++ot) {
      f16x8 bf = *(const f16x8*)&Bs[(wn * 128 + ot * 16 + lrow) * 32 + quad * 8];
      acc[0][ot] = __builtin_amdgcn_mfma_f32_16x16x32_f16(a0, bf, acc[0][ot], 0, 0, 0);
      acc[1][ot] = __builtin_amdgcn_mfma_f32_16x16x32_f16(a1, bf, acc[1][ot], 0, 0, 0);
    }
  }
  // epilogue: elu(acc/rowsum) * npm -> h1[bn][h*256+o] f16
#pragma unroll
  for (int mt = 0; mt < 2; ++mt) {
    int nr0 = wm * 32 + mt * 16 + quad * 4;
#pragma unroll
    for (int ot = 0; ot < 8; ++ot) {
      int o = wn * 128 + ot * 16 + lrow;
#pragma unroll
      for (int r = 0; r < 4; ++r) {
        int nr = nr0 + r;
        float v = acc[mt][ot][r] / rowsum[nr];
        v = v > 0.f ? v : expm1f(v);
        v *= npm[b * 256 + n0 + nr];
        h1[((size_t)(b * 256 + n0 + nr)) * 2048 + h * 256 + o] = (f16)v;
      }
    }
  }
}

// ---------------- fused attention layer 2 ----------------
// block = (nt in 4, oh in 2, b in 32). 64 rows x 256 cols (of 512) fp32 output.
__global__ __launch_bounds__(256, 2) void k_attn2(
    const f16* __restrict__ Wh2T, const float* __restrict__ e1g, const float* __restrict__ e2g,
    const int* __restrict__ adj, const float* __restrict__ npm, float* __restrict__ out) {
  int nt = blockIdx.x, oh = blockIdx.y, b = blockIdx.z;
  int n0 = nt * 64;
  __shared__ f16 P[64 * 256];
  __shared__ f16 Bs[256 * 32];
  __shared__ float e2s[256];
  __shared__ float red[256];
  __shared__ float rowsum[64];
  int tid = threadIdx.x;
  e2s[tid] = e2g[b * 256 + tid];
  __syncthreads();
  int row = tid >> 2, seg = tid & 3;
  float er = e1g[b * 256 + n0 + row];
  const int* adjrow = adj + ((size_t)(b * 256 + n0 + row)) * 256 + seg * 64;
  float mx = -3.0e38f;
  for (int j = 0; j < 64; ++j) {
    float v = er + e2s[seg * 64 + j];
    v = v > 0.f ? v : 0.2f * v;
    if (adjrow[j] == 0) v = NEGBIG;
    mx = fmaxf(mx, v);
  }
  red[tid] = mx;
  __syncthreads();
  mx = fmaxf(fmaxf(red[row * 4 + 0], red[row * 4 + 1]), fmaxf(red[row * 4 + 2], red[row * 4 + 3]));
  float sm = 0.f;
  for (int j = 0; j < 64; ++j) {
    float v = er + e2s[seg * 64 + j];
    v = v > 0.f ? v : 0.2f * v;
    if (adjrow[j] == 0) v = NEGBIG;
    float p = expf(v - mx);
    sm += p;
    P[row * 256 + seg * 64 + j] = (f16)p;
  }
  __syncthreads();
  red[tid] = sm;
  __syncthreads();
  if (seg == 0)
    rowsum[row] = red[row * 4] + red[row * 4 + 1] + red[row * 4 + 2] + red[row * 4 + 3];

  int wave = tid >> 6, lane = tid & 63;
  int wm = wave >> 1, wn = wave & 1;
  int lrow = lane & 15, quad = lane >> 4;
  f32x4 acc[2][8] = {};
  const f16* Bg = Wh2T + (size_t)b * 512 * 256 + (size_t)oh * 256 * 256;
  for (int k0 = 0; k0 < 256; k0 += 32) {
    __syncthreads();
#pragma unroll
    for (int j = 0; j < 4; ++j) {
      const int r0 = wave * 64 + j * 16;
      async16(Bg + (size_t)(r0 + (lane >> 2)) * 256 + k0 + (lane & 3) * 8, &Bs[r0 * 32]);
    }
    __syncthreads();
    f16x8 a0 = *(const f16x8*)&P[(wm * 32 + lrow) * 256 + k0 + quad * 8];
    f16x8 a1 = *(const f16x8*)&P[(wm * 32 + 16 + lrow) * 256 + k0 + quad * 8];
#pragma unroll
    for (int ot = 0; ot < 8; ++ot) {
      f16x8 bf = *(const f16x8*)&Bs[(wn * 128 + ot * 16 + lrow) * 32 + quad * 8];
      acc[0][ot] = __builtin_amdgcn_mfma_f32_16x16x32_f16(a0, bf, acc[0][ot], 0, 0, 0);
      acc[1][ot] = __builtin_amdgcn_mfma_f32_16x16x32_f16(a1, bf, acc[1][ot], 0, 0, 0);
    }
  }
  // epilogue: elu((acc/rowsum) * npm) -> out fp32
#pragma unroll
  for (int mt = 0; mt < 2; ++mt) {
    int nr0 = wm * 32 + mt * 16 + quad * 4;
#pragma unroll
    for (int ot = 0; ot < 8; ++ot) {
      int o = oh * 256 + wn * 128 + ot * 16 + lrow;
#pragma unroll
      for (int r = 0; r < 4; ++r) {
        int nr = nr0 + r;
        float v = acc[mt][ot][r] / rowsum[nr];
        v *= npm[b * 256 + n0 + nr];
        v = v > 0.f ? v : expm1f(v);
        out[((size_t)(b * 256 + n0 + nr)) * 512 + o] = v;
      }
    }
  }
}

extern "C" void kernel_launch(void* const* d_in, const int* in_sizes, int n_in,
                              void* d_out, int out_size, void* d_ws, size_t ws_size,
                              hipStream_t stream) {
  (void)in_sizes; (void)n_in; (void)out_size; (void)ws_size;
  const int*   fea   = (const int*)d_in[0];
  const int*   adj   = (const int*)d_in[1];
  const float* npm   = (const float*)d_in[2];
  const float* embed = (const float*)d_in[3];
  const float* Whd   = (const float*)d_in[4];
  const float* ah    = (const float*)d_in[5];
  const float* Wo    = (const float*)d_in[6];
  const float* ao    = (const float*)d_in[7];
  float* out = (float*)d_out;

  char* ws = (char*)d_ws;
  f16* x16  = (f16*)ws;  ws += (size_t)8192 * 320 * 2;
  f16* WcT  = (f16*)ws;  ws += (size_t)2048 * 320 * 2;
  f16* WoT  = (f16*)ws;  ws += (size_t)512 * 2048 * 2;
  f16* WhT  = (f16*)ws;  ws += (size_t)32 * 8 * 256 * 256 * 2;   // [b][h*256+o][n]
  f16* h1   = (f16*)ws;  ws += (size_t)8192 * 2048 * 2;          // [bn][h*256+o]
  f16* Wh2T = (f16*)ws;  ws += (size_t)32 * 512 * 256 * 2;       // [b][o2][n]
  float* e1  = (float*)ws; ws += (size_t)65536 * 4;
  float* e2  = (float*)ws; ws += (size_t)65536 * 4;
  float* e12 = (float*)ws; ws += (size_t)8192 * 4;
  float* e22 = (float*)ws; ws += (size_t)8192 * 4;

  k_prep_x<<<8192, 320, 0, stream>>>(fea, embed, x16);
  k_prep_wc<<<2048, 320, 0, stream>>>(Whd, WcT);
  k_prep_wo<<<512, 256, 0, stream>>>(Wo, WoT);

  k_gemm<320, 2048><<<dim3(16, 64), 256, 0, stream>>>(x16, WcT, WhT);
  k_edots<<<256, 256, 0, stream>>>(WhT, ah, e1, e2);
  k_attn1<<<dim3(4, 8, 32), 256, 0, stream>>>(WhT, e1, e2, adj, npm, h1);

  k_gemm<2048, 512><<<dim3(4, 64), 256, 0, stream>>>(h1, WoT, Wh2T);
  k_edots2<<<32, 256, 0, stream>>>(Wh2T, ao, e12, e22);
  k_attn2<<<dim3(4, 2, 32), 256, 0, stream>>>(Wh2T, e12, e22, adj, npm, out);
}

// Round 2
// 244.592 us; speedup vs baseline: 1.1526x; 1.1526x over previous
//
#include <hip/hip_runtime.h>
#include <math.h>

// GAT forward: B=32 N=256 F=300(pad 320) O=256 H=8 OUT=512

typedef _Float16 f16;
typedef __attribute__((ext_vector_type(8))) _Float16 f16x8;
typedef __attribute__((ext_vector_type(4))) _Float16 f16x4;
typedef __attribute__((ext_vector_type(4))) float f32x4;

__device__ __forceinline__ void async16(const void* g, void* lds) {
  __builtin_amdgcn_global_load_lds(
      (const __attribute__((address_space(1))) void*)g,
      (__attribute__((address_space(3))) void*)lds, 16, 0, 0);
}

// ---------------- prep kernels ----------------
__global__ void k_prep_x(const int* __restrict__ fea, const float* __restrict__ embed,
                         f16* __restrict__ x16) {
  int row = blockIdx.x;          // 8192
  int t = threadIdx.x;           // 320
  int tok = fea[row];
  float v = (t < 300) ? embed[tok * 300 + t] : 0.f;
  x16[(size_t)row * 320 + t] = (f16)v;
}

// W[h][t<300][o<256] -> WcT[(h*256+o)*320 + t], LDS 32x32 transpose
__global__ void k_prep_wc(const float* __restrict__ W, f16* __restrict__ WcT) {
  __shared__ float tile[32][33];
  int bx = blockIdx.x, by = blockIdx.y, h = blockIdx.z;   // (10, 8, 8)
  int tid = threadIdx.x;
  int c = tid & 31, q = tid >> 5;
#pragma unroll
  for (int i = 0; i < 4; ++i) {
    int tt = q + i * 8;
    int t = bx * 32 + tt;
    float v = (t < 300) ? W[((size_t)h * 300 + t) * 256 + by * 32 + c] : 0.f;
    tile[tt][c] = v;
  }
  __syncthreads();
#pragma unroll
  for (int i = 0; i < 4; ++i) {
    int oo = q + i * 8;
    int gc = h * 256 + by * 32 + oo;
    WcT[(size_t)gc * 320 + bx * 32 + c] = (f16)tile[c][oo];
  }
}

// W[k<2048][o2<512] -> WoT[o2*2048 + k]
__global__ void k_prep_wo(const float* __restrict__ W, f16* __restrict__ WoT) {
  __shared__ float tile[32][33];
  int bx = blockIdx.x, by = blockIdx.y;    // (64, 16)
  int tid = threadIdx.x;
  int c = tid & 31, q = tid >> 5;
#pragma unroll
  for (int i = 0; i < 4; ++i) {
    int kk = q + i * 8;
    tile[kk][c] = W[((size_t)bx * 32 + kk) * 512 + by * 32 + c];
  }
  __syncthreads();
#pragma unroll
  for (int i = 0; i < 4; ++i) {
    int oo = q + i * 8;
    WoT[((size_t)by * 32 + oo) * 2048 + bx * 32 + c] = (f16)tile[c][oo];
  }
}

// ---------------- GEMM: outT[b][col][n] = (A @ BT^T)^T, tile 128 x TN, BK=32 ----------------
template <int KDIM, int NCOLS, int TN>
__global__ __launch_bounds__(256, 2) void k_gemm(const f16* __restrict__ A,
                                                 const f16* __restrict__ BT,
                                                 f16* __restrict__ outT) {
  __shared__ f16 As[128 * 32];
  __shared__ f16 Bs[TN * 32];
  const int bx = blockIdx.x, by = blockIdx.y;
  const int tid = threadIdx.x;
  const int wave = tid >> 6, lane = tid & 63;
  const int wm = wave >> 1, wn = wave & 1;
  const int lrow = lane & 15, quad = lane >> 4;
  const int srow = lane >> 2;
  const int scol = (lane & 3) * 8;
  constexpr int NT = TN / 32;           // col tiles per wave

  f32x4 acc[4][NT] = {};
  const f16* Ag = A + (size_t)by * 128 * KDIM;
  const f16* Bg = BT + (size_t)bx * TN * KDIM;

  for (int k0 = 0; k0 < KDIM; k0 += 32) {
    __syncthreads();
#pragma unroll
    for (int j = 0; j < 2; ++j) {
      const int r0 = wave * 32 + j * 16;
      async16(Ag + (size_t)(r0 + srow) * KDIM + k0 + scol, &As[r0 * 32]);
    }
#pragma unroll
    for (int j = 0; j < TN / 64; ++j) {
      const int r0 = wave * (TN / 4) + j * 16;
      async16(Bg + (size_t)(r0 + srow) * KDIM + k0 + scol, &Bs[r0 * 32]);
    }
    __syncthreads();
    f16x8 af[4], bf[NT];
#pragma unroll
    for (int t = 0; t < 4; ++t)
      af[t] = *(const f16x8*)&As[(wm * 64 + t * 16 + lrow) * 32 + quad * 8];
#pragma unroll
    for (int t = 0; t < NT; ++t)
      bf[t] = *(const f16x8*)&Bs[(wn * (TN / 2) + t * 16 + lrow) * 32 + quad * 8];
#pragma unroll
    for (int mt = 0; mt < 4; ++mt)
#pragma unroll
      for (int nt = 0; nt < NT; ++nt)
        acc[mt][nt] = __builtin_amdgcn_mfma_f32_16x16x32_f16(af[mt], bf[nt], acc[mt][nt], 0, 0, 0);
  }

  const int b = (by * 128) >> 8;
  const int nbase0 = (by * 128) & 255;
#pragma unroll
  for (int mt = 0; mt < 4; ++mt) {
    const int nb = nbase0 + wm * 64 + mt * 16 + quad * 4;
#pragma unroll
    for (int nt = 0; nt < NT; ++nt) {
      const int gc = bx * TN + wn * (TN / 2) + nt * 16 + lrow;
      f16x4 v;
#pragma unroll
      for (int r = 0; r < 4; ++r) v[r] = (f16)acc[mt][nt][r];
      *(f16x4*)&outT[((size_t)b * NCOLS + gc) * 256 + nb] = v;
    }
  }
}

// ---------------- e1/e2 dots + e2 row max ----------------
__global__ void k_edots(const f16* __restrict__ WhT, const float* __restrict__ a_heads,
                        float* __restrict__ e1, float* __restrict__ e2,
                        float* __restrict__ e2m) {
  __shared__ float red[256];
  int bh = blockIdx.x;           // 256
  int h = bh & 7;
  int n = threadIdx.x;
  const f16* base = WhT + (size_t)bh * 65536 + n;
  float s1 = 0.f, s2 = 0.f;
  for (int o = 0; o < 256; ++o) {
    float w = (float)base[(size_t)o * 256];
    s1 += w * a_heads[h * 512 + o];
    s2 += w * a_heads[h * 512 + 256 + o];
  }
  e1[bh * 256 + n] = s1;
  e2[bh * 256 + n] = s2;
  red[n] = s2;
  __syncthreads();
  for (int s = 128; s > 0; s >>= 1) {
    if (n < s) red[n] = fmaxf(red[n], red[n + s]);
    __syncthreads();
  }
  if (n == 0) e2m[bh] = red[0];
}

__global__ void k_edots2(const f16* __restrict__ Wh2T, const float* __restrict__ a_out,
                         float* __restrict__ e1, float* __restrict__ e2,
                         float* __restrict__ e2m) {
  __shared__ float red[256];
  int b = blockIdx.x;            // 32
  int n = threadIdx.x;
  const f16* base = Wh2T + (size_t)b * 512 * 256 + n;
  float s1 = 0.f, s2 = 0.f;
  for (int o = 0; o < 512; ++o) {
    float w = (float)base[(size_t)o * 256];
    s1 += w * a_out[o];
    s2 += w * a_out[512 + o];
  }
  e1[b * 256 + n] = s1;
  e2[b * 256 + n] = s2;
  red[n] = s2;
  __syncthreads();
  for (int s = 128; s > 0; s >>= 1) {
    if (n < s) red[n] = fmaxf(red[n], red[n + s]);
    __syncthreads();
  }
  if (n == 0) e2m[b] = red[0];
}

#define PSTRIDE 264

// ---------------- fused attention layer 1 ----------------
// block=(nt 4, h 8, b 32). D[o=256][n=64]; A=Wh[o][m] from global, B=P[n][m] from LDS.
__global__ __launch_bounds__(256, 3) void k_attn1(
    const f16* __restrict__ WhT, const float* __restrict__ e1g, const float* __restrict__ e2g,
    const float* __restrict__ e2mg, const int* __restrict__ adj, const float* __restrict__ npm,
    f16* __restrict__ h1) {
  int nt0 = blockIdx.x, h = blockIdx.y, b = blockIdx.z;
  int bh = b * 8 + h;
  int n0 = nt0 * 64;
  __shared__ f16 P[64 * PSTRIDE];
  __shared__ float rinv[64];
  int tid = threadIdx.x;
  int wave = tid >> 6, lane = tid & 63;

  // softmax: wave handles rows wave, wave+4, ...; lanes cover m = lane*4..+3
  float4 e2v = *(const float4*)&e2g[bh * 256 + lane * 4];
  float e2m = e2mg[bh];
#pragma unroll 4
  for (int i = 0; i < 16; ++i) {
    int row = i * 4 + wave;
    int gn = b * 256 + n0 + row;
    float er = e1g[bh * 256 + n0 + row];
    float sh = er + e2m;
    sh = sh > 0.f ? sh : 0.2f * sh;     // upper bound of row max
    int4 aj = *(const int4*)&adj[(size_t)gn * 256 + lane * 4];
    float p0, p1, p2, p3;
    {
      float v = er + e2v.x; v = v > 0.f ? v : 0.2f * v;
      p0 = aj.x ? __expf(v - sh) : 0.f;
      v = er + e2v.y; v = v > 0.f ? v : 0.2f * v;
      p1 = aj.y ? __expf(v - sh) : 0.f;
      v = er + e2v.z; v = v > 0.f ? v : 0.2f * v;
      p2 = aj.z ? __expf(v - sh) : 0.f;
      v = er + e2v.w; v = v > 0.f ? v : 0.2f * v;
      p3 = aj.w ? __expf(v - sh) : 0.f;
    }
    float sm = p0 + p1 + p2 + p3;
#pragma unroll
    for (int m = 1; m < 64; m <<= 1) sm += __shfl_xor(sm, m);
    f16x4 pw; pw[0] = (f16)p0; pw[1] = (f16)p1; pw[2] = (f16)p2; pw[3] = (f16)p3;
    *(f16x4*)&P[row * PSTRIDE + lane * 4] = pw;
    if (lane == 0) rinv[row] = 1.f / sm;
  }
  __syncthreads();

  // PV
  int lrow = lane & 15, quad = lane >> 4;
  f32x4 acc[4][4] = {};
  const f16* Ag = WhT + (size_t)bh * 65536;
#pragma unroll 2
  for (int k0 = 0; k0 < 256; k0 += 32) {
    f16x8 af[4], bf[4];
#pragma unroll
    for (int mt = 0; mt < 4; ++mt)
      af[mt] = *(const f16x8*)&Ag[(size_t)(wave * 64 + mt * 16 + lrow) * 256 + k0 + quad * 8];
#pragma unroll
    for (int nt = 0; nt < 4; ++nt)
      bf[nt] = *(const f16x8*)&P[(nt * 16 + lrow) * PSTRIDE + k0 + quad * 8];
#pragma unroll
    for (int mt = 0; mt < 4; ++mt)
#pragma unroll
      for (int nt = 0; nt < 4; ++nt)
        acc[mt][nt] = __builtin_amdgcn_mfma_f32_16x16x32_f16(af[mt], bf[nt], acc[mt][nt], 0, 0, 0);
  }
  // epilogue: lane holds 4 consecutive o (rows), col n = nt*16+lrow
#pragma unroll
  for (int nt = 0; nt < 4; ++nt) {
    int nloc = nt * 16 + lrow;
    int gn = b * 256 + n0 + nloc;
    float rv = rinv[nloc];
    float pm = npm[gn];
#pragma unroll
    for (int mt = 0; mt < 4; ++mt) {
      int o0 = wave * 64 + mt * 16 + quad * 4;
      f16x4 st;
#pragma unroll
      for (int r = 0; r < 4; ++r) {
        float v = acc[mt][nt][r] * rv;
        v = v > 0.f ? v : (__expf(v) - 1.f);
        st[r] = (f16)(v * pm);
      }
      *(f16x4*)&h1[(size_t)gn * 2048 + h * 256 + o0] = st;
    }
  }
}

// ---------------- fused attention layer 2 ----------------
// block=(nt 4, oh 2, b 32). D[o=256 of 512][n=64], fp32 out.
__global__ __launch_bounds__(256, 3) void k_attn2(
    const f16* __restrict__ Wh2T, const float* __restrict__ e1g, const float* __restrict__ e2g,
    const float* __restrict__ e2mg, const int* __restrict__ adj, const float* __restrict__ npm,
    float* __restrict__ out) {
  int nt0 = blockIdx.x, oh = blockIdx.y, b = blockIdx.z;
  int n0 = nt0 * 64;
  __shared__ f16 P[64 * PSTRIDE];
  __shared__ float rinv[64];
  int tid = threadIdx.x;
  int wave = tid >> 6, lane = tid & 63;

  float4 e2v = *(const float4*)&e2g[b * 256 + lane * 4];
  float e2m = e2mg[b];
#pragma unroll 4
  for (int i = 0; i < 16; ++i) {
    int row = i * 4 + wave;
    int gn = b * 256 + n0 + row;
    float er = e1g[b * 256 + n0 + row];
    float sh = er + e2m;
    sh = sh > 0.f ? sh : 0.2f * sh;
    int4 aj = *(const int4*)&adj[(size_t)gn * 256 + lane * 4];
    float p0, p1, p2, p3;
    {
      float v = er + e2v.x; v = v > 0.f ? v : 0.2f * v;
      p0 = aj.x ? __expf(v - sh) : 0.f;
      v = er + e2v.y; v = v > 0.f ? v : 0.2f * v;
      p1 = aj.y ? __expf(v - sh) : 0.f;
      v = er + e2v.z; v = v > 0.f ? v : 0.2f * v;
      p2 = aj.z ? __expf(v - sh) : 0.f;
      v = er + e2v.w; v = v > 0.f ? v : 0.2f * v;
      p3 = aj.w ? __expf(v - sh) : 0.f;
    }
    float sm = p0 + p1 + p2 + p3;
#pragma unroll
    for (int m = 1; m < 64; m <<= 1) sm += __shfl_xor(sm, m);
    f16x4 pw; pw[0] = (f16)p0; pw[1] = (f16)p1; pw[2] = (f16)p2; pw[3] = (f16)p3;
    *(f16x4*)&P[row * PSTRIDE + lane * 4] = pw;
    if (lane == 0) rinv[row] = 1.f / sm;
  }
  __syncthreads();

  int lrow = lane & 15, quad = lane >> 4;
  f32x4 acc[4][4] = {};
  const f16* Ag = Wh2T + (size_t)b * 512 * 256 + (size_t)oh * 65536;
#pragma unroll 2
  for (int k0 = 0; k0 < 256; k0 += 32) {
    f16x8 af[4], bf[4];
#pragma unroll
    for (int mt = 0; mt < 4; ++mt)
      af[mt] = *(const f16x8*)&Ag[(size_t)(wave * 64 + mt * 16 + lrow) * 256 + k0 + quad * 8];
#pragma unroll
    for (int nt = 0; nt < 4; ++nt)
      bf[nt] = *(const f16x8*)&P[(nt * 16 + lrow) * PSTRIDE + k0 + quad * 8];
#pragma unroll
    for (int mt = 0; mt < 4; ++mt)
#pragma unroll
      for (int nt = 0; nt < 4; ++nt)
        acc[mt][nt] = __builtin_amdgcn_mfma_f32_16x16x32_f16(af[mt], bf[nt], acc[mt][nt], 0, 0, 0);
  }
#pragma unroll
  for (int nt = 0; nt < 4; ++nt) {
    int nloc = nt * 16 + lrow;
    int gn = b * 256 + n0 + nloc;
    float rv = rinv[nloc];
    float pm = npm[gn];
#pragma unroll
    for (int mt = 0; mt < 4; ++mt) {
      int o0 = oh * 256 + wave * 64 + mt * 16 + quad * 4;
      float4 st;
      float v0 = acc[mt][nt][0] * rv * pm;
      float v1 = acc[mt][nt][1] * rv * pm;
      float v2 = acc[mt][nt][2] * rv * pm;
      float v3 = acc[mt][nt][3] * rv * pm;
      st.x = v0 > 0.f ? v0 : (__expf(v0) - 1.f);
      st.y = v1 > 0.f ? v1 : (__expf(v1) - 1.f);
      st.z = v2 > 0.f ? v2 : (__expf(v2) - 1.f);
      st.w = v3 > 0.f ? v3 : (__expf(v3) - 1.f);
      *(float4*)&out[(size_t)gn * 512 + o0] = st;
    }
  }
}

extern "C" void kernel_launch(void* const* d_in, const int* in_sizes, int n_in,
                              void* d_out, int out_size, void* d_ws, size_t ws_size,
                              hipStream_t stream) {
  (void)in_sizes; (void)n_in; (void)out_size; (void)ws_size;
  const int*   fea   = (const int*)d_in[0];
  const int*   adj   = (const int*)d_in[1];
  const float* npm   = (const float*)d_in[2];
  const float* embed = (const float*)d_in[3];
  const float* Whd   = (const float*)d_in[4];
  const float* ah    = (const float*)d_in[5];
  const float* Wo    = (const float*)d_in[6];
  const float* ao    = (const float*)d_in[7];
  float* out = (float*)d_out;

  char* ws = (char*)d_ws;
  f16* x16  = (f16*)ws;  ws += (size_t)8192 * 320 * 2;
  f16* WcT  = (f16*)ws;  ws += (size_t)2048 * 320 * 2;
  f16* WoT  = (f16*)ws;  ws += (size_t)512 * 2048 * 2;
  f16* WhT  = (f16*)ws;  ws += (size_t)32 * 8 * 256 * 256 * 2;   // [b][h*256+o][n]
  f16* h1   = (f16*)ws;  ws += (size_t)8192 * 2048 * 2;          // [bn][h*256+o]
  f16* Wh2T = (f16*)ws;  ws += (size_t)32 * 512 * 256 * 2;       // [b][o2][n]
  float* e1  = (float*)ws; ws += (size_t)65536 * 4;
  float* e2  = (float*)ws; ws += (size_t)65536 * 4;
  float* e12 = (float*)ws; ws += (size_t)8192 * 4;
  float* e22 = (float*)ws; ws += (size_t)8192 * 4;
  float* e2m1 = (float*)ws; ws += (size_t)256 * 4;
  float* e2m2 = (float*)ws; ws += (size_t)32 * 4;

  k_prep_x<<<8192, 320, 0, stream>>>(fea, embed, x16);
  k_prep_wc<<<dim3(10, 8, 8), 256, 0, stream>>>(Whd, WcT);
  k_prep_wo<<<dim3(64, 16), 256, 0, stream>>>(Wo, WoT);

  k_gemm<320, 2048, 128><<<dim3(16, 64), 256, 0, stream>>>(x16, WcT, WhT);
  k_edots<<<256, 256, 0, stream>>>(WhT, ah, e1, e2, e2m1);
  k_attn1<<<dim3(4, 8, 32), 256, 0, stream>>>(WhT, e1, e2, e2m1, adj, npm, h1);

  k_gemm<2048, 512, 64><<<dim3(8, 64), 256, 0, stream>>>(h1, WoT, Wh2T);
  k_edots2<<<32, 256, 0, stream>>>(Wh2T, ao, e12, e22, e2m2);
  k_attn2<<<dim3(4, 2, 32), 256, 0, stream>>>(Wh2T, e12, e22, e2m2, adj, npm, out);
}

// Round 3
// 236.698 us; speedup vs baseline: 1.1910x; 1.0333x over previous
//
#include <hip/hip_runtime.h>
#include <math.h>

// GAT forward: B=32 N=256 F=300(pad 320) O=256 H=8 OUT=512

typedef _Float16 f16;
typedef __attribute__((ext_vector_type(8))) _Float16 f16x8;
typedef __attribute__((ext_vector_type(4))) _Float16 f16x4;
typedef __attribute__((ext_vector_type(4))) float f32x4;

__device__ __forceinline__ void async16(const void* g, void* lds) {
  __builtin_amdgcn_global_load_lds(
      (const __attribute__((address_space(1))) void*)g,
      (__attribute__((address_space(3))) void*)lds, 16, 0, 0);
}

// ---------------- prep kernels ----------------
__global__ void k_prep_x(const int* __restrict__ fea, const float* __restrict__ embed,
                         f16* __restrict__ x16) {
  int row = blockIdx.x;          // 8192
  int t = threadIdx.x;           // 320
  int tok = fea[row];
  float v = (t < 300) ? embed[tok * 300 + t] : 0.f;
  x16[(size_t)row * 320 + t] = (f16)v;
}

// W[h][t<300][o<256] -> WcT[(h*256+o)*320 + t], LDS 32x32 transpose
__global__ void k_prep_wc(const float* __restrict__ W, f16* __restrict__ WcT) {
  __shared__ float tile[32][33];
  int bx = blockIdx.x, by = blockIdx.y, h = blockIdx.z;   // (10, 8, 8)
  int tid = threadIdx.x;
  int c = tid & 31, q = tid >> 5;
#pragma unroll
  for (int i = 0; i < 4; ++i) {
    int tt = q + i * 8;
    int t = bx * 32 + tt;
    float v = (t < 300) ? W[((size_t)h * 300 + t) * 256 + by * 32 + c] : 0.f;
    tile[tt][c] = v;
  }
  __syncthreads();
#pragma unroll
  for (int i = 0; i < 4; ++i) {
    int oo = q + i * 8;
    int gc = h * 256 + by * 32 + oo;
    WcT[(size_t)gc * 320 + bx * 32 + c] = (f16)tile[c][oo];
  }
}

// W[k<2048][o2<512] -> WoT[o2*2048 + k]
__global__ void k_prep_wo(const float* __restrict__ W, f16* __restrict__ WoT) {
  __shared__ float tile[32][33];
  int bx = blockIdx.x, by = blockIdx.y;    // (64, 16)
  int tid = threadIdx.x;
  int c = tid & 31, q = tid >> 5;
#pragma unroll
  for (int i = 0; i < 4; ++i) {
    int kk = q + i * 8;
    tile[kk][c] = W[((size_t)bx * 32 + kk) * 512 + by * 32 + c];
  }
  __syncthreads();
#pragma unroll
  for (int i = 0; i < 4; ++i) {
    int oo = q + i * 8;
    WoT[((size_t)by * 32 + oo) * 2048 + bx * 32 + c] = (f16)tile[c][oo];
  }
}

// ---------------- GEMM: outT[b][col][n] = (A @ BT^T)^T, tile 128 x TN, BK=32 ----------------
// XCD swizzle: blockIdx.x = A-row-tile (fastest). Col-tiles of the same A-tile
// differ by gridDim.x (64, mult of 8) in linear index -> same XCD -> A-tile
// fetched once per XCD L2 instead of once per block.
template <int KDIM, int NCOLS, int TN>
__global__ __launch_bounds__(256, 4) void k_gemm(const f16* __restrict__ A,
                                                 const f16* __restrict__ BT,
                                                 f16* __restrict__ outT) {
  __shared__ f16 As[128 * 32];
  __shared__ f16 Bs[TN * 32];
  const int by = blockIdx.x, bx = blockIdx.y;   // swizzled
  const int tid = threadIdx.x;
  const int wave = tid >> 6, lane = tid & 63;
  const int wm = wave >> 1, wn = wave & 1;
  const int lrow = lane & 15, quad = lane >> 4;
  const int srow = lane >> 2;
  const int scol = (lane & 3) * 8;
  constexpr int NT = TN / 32;           // col tiles per wave

  f32x4 acc[4][NT] = {};
  const f16* Ag = A + (size_t)by * 128 * KDIM;
  const f16* Bg = BT + (size_t)bx * TN * KDIM;

  for (int k0 = 0; k0 < KDIM; k0 += 32) {
    __syncthreads();
#pragma unroll
    for (int j = 0; j < 2; ++j) {
      const int r0 = wave * 32 + j * 16;
      async16(Ag + (size_t)(r0 + srow) * KDIM + k0 + scol, &As[r0 * 32]);
    }
#pragma unroll
    for (int j = 0; j < TN / 64; ++j) {
      const int r0 = wave * (TN / 4) + j * 16;
      async16(Bg + (size_t)(r0 + srow) * KDIM + k0 + scol, &Bs[r0 * 32]);
    }
    __syncthreads();
    f16x8 af[4], bf[NT];
#pragma unroll
    for (int t = 0; t < 4; ++t)
      af[t] = *(const f16x8*)&As[(wm * 64 + t * 16 + lrow) * 32 + quad * 8];
#pragma unroll
    for (int t = 0; t < NT; ++t)
      bf[t] = *(const f16x8*)&Bs[(wn * (TN / 2) + t * 16 + lrow) * 32 + quad * 8];
#pragma unroll
    for (int mt = 0; mt < 4; ++mt)
#pragma unroll
      for (int nt = 0; nt < NT; ++nt)
        acc[mt][nt] = __builtin_amdgcn_mfma_f32_16x16x32_f16(af[mt], bf[nt], acc[mt][nt], 0, 0, 0);
  }

  const int b = (by * 128) >> 8;
  const int nbase0 = (by * 128) & 255;
#pragma unroll
  for (int mt = 0; mt < 4; ++mt) {
    const int nb = nbase0 + wm * 64 + mt * 16 + quad * 4;
#pragma unroll
    for (int nt = 0; nt < NT; ++nt) {
      const int gc = bx * TN + wn * (TN / 2) + nt * 16 + lrow;
      f16x4 v;
#pragma unroll
      for (int r = 0; r < 4; ++r) v[r] = (f16)acc[mt][nt][r];
      *(f16x4*)&outT[((size_t)b * NCOLS + gc) * 256 + nb] = v;
    }
  }
}

// ---------------- e1/e2 dots + e2 row max ----------------
__global__ void k_edots(const f16* __restrict__ WhT, const float* __restrict__ a_heads,
                        float* __restrict__ e1, float* __restrict__ e2,
                        float* __restrict__ e2m) {
  __shared__ float red[256];
  int bh = blockIdx.x;           // 256
  int h = bh & 7;
  int n = threadIdx.x;
  const f16* base = WhT + (size_t)bh * 65536 + n;
  float s1 = 0.f, s2 = 0.f;
  for (int o = 0; o < 256; ++o) {
    float w = (float)base[(size_t)o * 256];
    s1 += w * a_heads[h * 512 + o];
    s2 += w * a_heads[h * 512 + 256 + o];
  }
  e1[bh * 256 + n] = s1;
  e2[bh * 256 + n] = s2;
  red[n] = s2;
  __syncthreads();
  for (int s = 128; s > 0; s >>= 1) {
    if (n < s) red[n] = fmaxf(red[n], red[n + s]);
    __syncthreads();
  }
  if (n == 0) e2m[bh] = red[0];
}

__global__ void k_edots2(const f16* __restrict__ Wh2T, const float* __restrict__ a_out,
                         float* __restrict__ e1, float* __restrict__ e2,
                         float* __restrict__ e2m) {
  __shared__ float red[256];
  int b = blockIdx.x;            // 32
  int n = threadIdx.x;
  const f16* base = Wh2T + (size_t)b * 512 * 256 + n;
  float s1 = 0.f, s2 = 0.f;
  for (int o = 0; o < 512; ++o) {
    float w = (float)base[(size_t)o * 256];
    s1 += w * a_out[o];
    s2 += w * a_out[512 + o];
  }
  e1[b * 256 + n] = s1;
  e2[b * 256 + n] = s2;
  red[n] = s2;
  __syncthreads();
  for (int s = 128; s > 0; s >>= 1) {
    if (n < s) red[n] = fmaxf(red[n], red[n + s]);
    __syncthreads();
  }
  if (n == 0) e2m[b] = red[0];
}

#define PSTRIDE 264

// ---------------- fused attention layer 1 ----------------
// grid (h=8, b=32, nt=4): nt-blocks of one (b,h) differ by 256 in linear index
// (mult of 8) -> same XCD -> Wh[b,h] (128 KB) fetched once per XCD.
__global__ __launch_bounds__(256, 3) void k_attn1(
    const f16* __restrict__ WhT, const float* __restrict__ e1g, const float* __restrict__ e2g,
    const float* __restrict__ e2mg, const int* __restrict__ adj, const float* __restrict__ npm,
    f16* __restrict__ h1) {
  int h = blockIdx.x, b = blockIdx.y, nt0 = blockIdx.z;   // swizzled
  int bh = b * 8 + h;
  int n0 = nt0 * 64;
  __shared__ f16 P[64 * PSTRIDE];
  __shared__ float rinv[64];
  int tid = threadIdx.x;
  int wave = tid >> 6, lane = tid & 63;

  // softmax: wave handles rows wave, wave+4, ...; lanes cover m = lane*4..+3
  float4 e2v = *(const float4*)&e2g[bh * 256 + lane * 4];
  float e2m = e2mg[bh];
#pragma unroll 4
  for (int i = 0; i < 16; ++i) {
    int row = i * 4 + wave;
    int gn = b * 256 + n0 + row;
    float er = e1g[bh * 256 + n0 + row];
    float sh = er + e2m;
    sh = sh > 0.f ? sh : 0.2f * sh;     // upper bound of row max
    int4 aj = *(const int4*)&adj[(size_t)gn * 256 + lane * 4];
    float p0, p1, p2, p3;
    {
      float v = er + e2v.x; v = v > 0.f ? v : 0.2f * v;
      p0 = aj.x ? __expf(v - sh) : 0.f;
      v = er + e2v.y; v = v > 0.f ? v : 0.2f * v;
      p1 = aj.y ? __expf(v - sh) : 0.f;
      v = er + e2v.z; v = v > 0.f ? v : 0.2f * v;
      p2 = aj.z ? __expf(v - sh) : 0.f;
      v = er + e2v.w; v = v > 0.f ? v : 0.2f * v;
      p3 = aj.w ? __expf(v - sh) : 0.f;
    }
    float sm = p0 + p1 + p2 + p3;
#pragma unroll
    for (int m = 1; m < 64; m <<= 1) sm += __shfl_xor(sm, m);
    f16x4 pw; pw[0] = (f16)p0; pw[1] = (f16)p1; pw[2] = (f16)p2; pw[3] = (f16)p3;
    *(f16x4*)&P[row * PSTRIDE + lane * 4] = pw;
    if (lane == 0) rinv[row] = 1.f / sm;
  }
  __syncthreads();

  // PV: D[o][n]; A=Wh[o][m] from global (L2-hot), B=P[n][m] from LDS
  int lrow = lane & 15, quad = lane >> 4;
  f32x4 acc[4][4] = {};
  const f16* Ag = WhT + (size_t)bh * 65536;
#pragma unroll 2
  for (int k0 = 0; k0 < 256; k0 += 32) {
    f16x8 af[4], bf[4];
#pragma unroll
    for (int mt = 0; mt < 4; ++mt)
      af[mt] = *(const f16x8*)&Ag[(size_t)(wave * 64 + mt * 16 + lrow) * 256 + k0 + quad * 8];
#pragma unroll
    for (int nt = 0; nt < 4; ++nt)
      bf[nt] = *(const f16x8*)&P[(nt * 16 + lrow) * PSTRIDE + k0 + quad * 8];
#pragma unroll
    for (int mt = 0; mt < 4; ++mt)
#pragma unroll
      for (int nt = 0; nt < 4; ++nt)
        acc[mt][nt] = __builtin_amdgcn_mfma_f32_16x16x32_f16(af[mt], bf[nt], acc[mt][nt], 0, 0, 0);
  }
  // epilogue: lane holds 4 consecutive o (rows), col n = nt*16+lrow
#pragma unroll
  for (int nt = 0; nt < 4; ++nt) {
    int nloc = nt * 16 + lrow;
    int gn = b * 256 + n0 + nloc;
    float rv = rinv[nloc];
    float pm = npm[gn];
#pragma unroll
    for (int mt = 0; mt < 4; ++mt) {
      int o0 = wave * 64 + mt * 16 + quad * 4;
      f16x4 st;
#pragma unroll
      for (int r = 0; r < 4; ++r) {
        float v = acc[mt][nt][r] * rv;
        v = v > 0.f ? v : (__expf(v) - 1.f);
        st[r] = (f16)(v * pm);
      }
      *(f16x4*)&h1[(size_t)gn * 2048 + h * 256 + o0] = st;
    }
  }
}

// ---------------- fused attention layer 2 ----------------
// grid (oh=2, b=32, nt=4): nt-blocks of one (b,oh) differ by 64 (mult of 8) -> same XCD.
__global__ __launch_bounds__(256, 3) void k_attn2(
    const f16* __restrict__ Wh2T, const float* __restrict__ e1g, const float* __restrict__ e2g,
    const float* __restrict__ e2mg, const int* __restrict__ adj, const float* __restrict__ npm,
    float* __restrict__ out) {
  int oh = blockIdx.x, b = blockIdx.y, nt0 = blockIdx.z;  // swizzled
  int n0 = nt0 * 64;
  __shared__ f16 P[64 * PSTRIDE];
  __shared__ float rinv[64];
  int tid = threadIdx.x;
  int wave = tid >> 6, lane = tid & 63;

  float4 e2v = *(const float4*)&e2g[b * 256 + lane * 4];
  float e2m = e2mg[b];
#pragma unroll 4
  for (int i = 0; i < 16; ++i) {
    int row = i * 4 + wave;
    int gn = b * 256 + n0 + row;
    float er = e1g[b * 256 + n0 + row];
    float sh = er + e2m;
    sh = sh > 0.f ? sh : 0.2f * sh;
    int4 aj = *(const int4*)&adj[(size_t)gn * 256 + lane * 4];
    float p0, p1, p2, p3;
    {
      float v = er + e2v.x; v = v > 0.f ? v : 0.2f * v;
      p0 = aj.x ? __expf(v - sh) : 0.f;
      v = er + e2v.y; v = v > 0.f ? v : 0.2f * v;
      p1 = aj.y ? __expf(v - sh) : 0.f;
      v = er + e2v.z; v = v > 0.f ? v : 0.2f * v;
      p2 = aj.z ? __expf(v - sh) : 0.f;
      v = er + e2v.w; v = v > 0.f ? v : 0.2f * v;
      p3 = aj.w ? __expf(v - sh) : 0.f;
    }
    float sm = p0 + p1 + p2 + p3;
#pragma unroll
    for (int m = 1; m < 64; m <<= 1) sm += __shfl_xor(sm, m);
    f16x4 pw; pw[0] = (f16)p0; pw[1] = (f16)p1; pw[2] = (f16)p2; pw[3] = (f16)p3;
    *(f16x4*)&P[row * PSTRIDE + lane * 4] = pw;
    if (lane == 0) rinv[row] = 1.f / sm;
  }
  __syncthreads();

  int lrow = lane & 15, quad = lane >> 4;
  f32x4 acc[4][4] = {};
  const f16* Ag = Wh2T + (size_t)b * 512 * 256 + (size_t)oh * 65536;
#pragma unroll 2
  for (int k0 = 0; k0 < 256; k0 += 32) {
    f16x8 af[4], bf[4];
#pragma unroll
    for (int mt = 0; mt < 4; ++mt)
      af[mt] = *(const f16x8*)&Ag[(size_t)(wave * 64 + mt * 16 + lrow) * 256 + k0 + quad * 8];
#pragma unroll
    for (int nt = 0; nt < 4; ++nt)
      bf[nt] = *(const f16x8*)&P[(nt * 16 + lrow) * PSTRIDE + k0 + quad * 8];
#pragma unroll
    for (int mt = 0; mt < 4; ++mt)
#pragma unroll
      for (int nt = 0; nt < 4; ++nt)
        acc[mt][nt] = __builtin_amdgcn_mfma_f32_16x16x32_f16(af[mt], bf[nt], acc[mt][nt], 0, 0, 0);
  }
#pragma unroll
  for (int nt = 0; nt < 4; ++nt) {
    int nloc = nt * 16 + lrow;
    int gn = b * 256 + n0 + nloc;
    float rv = rinv[nloc];
    float pm = npm[gn];
#pragma unroll
    for (int mt = 0; mt < 4; ++mt) {
      int o0 = oh * 256 + wave * 64 + mt * 16 + quad * 4;
      float4 st;
      float v0 = acc[mt][nt][0] * rv * pm;
      float v1 = acc[mt][nt][1] * rv * pm;
      float v2 = acc[mt][nt][2] * rv * pm;
      float v3 = acc[mt][nt][3] * rv * pm;
      st.x = v0 > 0.f ? v0 : (__expf(v0) - 1.f);
      st.y = v1 > 0.f ? v1 : (__expf(v1) - 1.f);
      st.z = v2 > 0.f ? v2 : (__expf(v2) - 1.f);
      st.w = v3 > 0.f ? v3 : (__expf(v3) - 1.f);
      *(float4*)&out[(size_t)gn * 512 + o0] = st;
    }
  }
}

extern "C" void kernel_launch(void* const* d_in, const int* in_sizes, int n_in,
                              void* d_out, int out_size, void* d_ws, size_t ws_size,
                              hipStream_t stream) {
  (void)in_sizes; (void)n_in; (void)out_size; (void)ws_size;
  const int*   fea   = (const int*)d_in[0];
  const int*   adj   = (const int*)d_in[1];
  const float* npm   = (const float*)d_in[2];
  const float* embed = (const float*)d_in[3];
  const float* Whd   = (const float*)d_in[4];
  const float* ah    = (const float*)d_in[5];
  const float* Wo    = (const float*)d_in[6];
  const float* ao    = (const float*)d_in[7];
  float* out = (float*)d_out;

  char* ws = (char*)d_ws;
  f16* x16  = (f16*)ws;  ws += (size_t)8192 * 320 * 2;
  f16* WcT  = (f16*)ws;  ws += (size_t)2048 * 320 * 2;
  f16* WoT  = (f16*)ws;  ws += (size_t)512 * 2048 * 2;
  f16* WhT  = (f16*)ws;  ws += (size_t)32 * 8 * 256 * 256 * 2;   // [b][h*256+o][n]
  f16* h1   = (f16*)ws;  ws += (size_t)8192 * 2048 * 2;          // [bn][h*256+o]
  f16* Wh2T = (f16*)ws;  ws += (size_t)32 * 512 * 256 * 2;       // [b][o2][n]
  float* e1  = (float*)ws; ws += (size_t)65536 * 4;
  float* e2  = (float*)ws; ws += (size_t)65536 * 4;
  float* e12 = (float*)ws; ws += (size_t)8192 * 4;
  float* e22 = (float*)ws; ws += (size_t)8192 * 4;
  float* e2m1 = (float*)ws; ws += (size_t)256 * 4;
  float* e2m2 = (float*)ws; ws += (size_t)32 * 4;

  k_prep_x<<<8192, 320, 0, stream>>>(fea, embed, x16);
  k_prep_wc<<<dim3(10, 8, 8), 256, 0, stream>>>(Whd, WcT);
  k_prep_wo<<<dim3(64, 16), 256, 0, stream>>>(Wo, WoT);

  // swizzled grids: A-row-tile fastest (blockIdx.x)
  k_gemm<320, 2048, 128><<<dim3(64, 16), 256, 0, stream>>>(x16, WcT, WhT);
  k_edots<<<256, 256, 0, stream>>>(WhT, ah, e1, e2, e2m1);
  k_attn1<<<dim3(8, 32, 4), 256, 0, stream>>>(WhT, e1, e2, e2m1, adj, npm, h1);

  k_gemm<2048, 512, 64><<<dim3(64, 8), 256, 0, stream>>>(h1, WoT, Wh2T);
  k_edots2<<<32, 256, 0, stream>>>(Wh2T, ao, e12, e22, e2m2);
  k_attn2<<<dim3(2, 32, 4), 256, 0, stream>>>(Wh2T, e12, e22, e2m2, adj, npm, out);
}

// Round 4
// 205.747 us; speedup vs baseline: 1.3702x; 1.1504x over previous
//
#include <hip/hip_runtime.h>
#include <math.h>

// GAT forward: B=32 N=256 F=300(pad 320) O=256 H=8 OUT=512

typedef _Float16 f16;
typedef __attribute__((ext_vector_type(8))) _Float16 f16x8;
typedef __attribute__((ext_vector_type(4))) _Float16 f16x4;
typedef __attribute__((ext_vector_type(4))) float f32x4;

__device__ __forceinline__ void async16(const void* g, void* lds) {
  __builtin_amdgcn_global_load_lds(
      (const __attribute__((address_space(1))) void*)g,
      (__attribute__((address_space(3))) void*)lds, 16, 0, 0);
}

// ---------------- prep kernels ----------------
__global__ void k_prep_x(const int* __restrict__ fea, const float* __restrict__ embed,
                         f16* __restrict__ x16) {
  int row = blockIdx.x;          // 8192
  int t = threadIdx.x;           // 320
  int tok = fea[row];
  float v = (t < 300) ? embed[tok * 300 + t] : 0.f;
  x16[(size_t)row * 320 + t] = (f16)v;
}

// W[h][t<300][o<256] -> WcT[(h*256+o)*320 + t], LDS 32x32 transpose
__global__ void k_prep_wc(const float* __restrict__ W, f16* __restrict__ WcT) {
  __shared__ float tile[32][33];
  int bx = blockIdx.x, by = blockIdx.y, h = blockIdx.z;   // (10, 8, 8)
  int tid = threadIdx.x;
  int c = tid & 31, q = tid >> 5;
#pragma unroll
  for (int i = 0; i < 4; ++i) {
    int tt = q + i * 8;
    int t = bx * 32 + tt;
    float v = (t < 300) ? W[((size_t)h * 300 + t) * 256 + by * 32 + c] : 0.f;
    tile[tt][c] = v;
  }
  __syncthreads();
#pragma unroll
  for (int i = 0; i < 4; ++i) {
    int oo = q + i * 8;
    int gc = h * 256 + by * 32 + oo;
    WcT[(size_t)gc * 320 + bx * 32 + c] = (f16)tile[c][oo];
  }
}

// W[k<2048][o2<512] -> WoT[o2*2048 + k]
__global__ void k_prep_wo(const float* __restrict__ W, f16* __restrict__ WoT) {
  __shared__ float tile[32][33];
  int bx = blockIdx.x, by = blockIdx.y;    // (64, 16)
  int tid = threadIdx.x;
  int c = tid & 31, q = tid >> 5;
#pragma unroll
  for (int i = 0; i < 4; ++i) {
    int kk = q + i * 8;
    tile[kk][c] = W[((size_t)bx * 32 + kk) * 512 + by * 32 + c];
  }
  __syncthreads();
#pragma unroll
  for (int i = 0; i < 4; ++i) {
    int oo = q + i * 8;
    WoT[((size_t)by * 32 + oo) * 2048 + bx * 32 + c] = (f16)tile[c][oo];
  }
}

// ---------------- GEMM + fused e-dots ----------------
// outT[b][col][n] = (A @ BT^T)^T, tile 128 x TN, BK=32.
// blockIdx.x = A-row-tile (fastest) -> col-tiles sharing an A-tile land on one XCD.
// EDOT=1: e1/e2 partial dots vs a_heads[h][...]; EDOT=2: vs a_out (atomicAdd, pre-zeroed).
template <int KDIM, int NCOLS, int TN, int EDOT>
__global__ __launch_bounds__(256, 4) void k_gemm(const f16* __restrict__ A,
                                                 const f16* __restrict__ BT,
                                                 f16* __restrict__ outT,
                                                 const float* __restrict__ avec,
                                                 float* __restrict__ e1,
                                                 float* __restrict__ e2) {
  __shared__ f16 As[128 * 32];
  __shared__ f16 Bs[TN * 32];
  const int by = blockIdx.x, bx = blockIdx.y;   // swizzled
  const int tid = threadIdx.x;
  const int wave = tid >> 6, lane = tid & 63;
  const int wm = wave >> 1, wn = wave & 1;
  const int lrow = lane & 15, quad = lane >> 4;
  const int srow = lane >> 2;
  const int scol = (lane & 3) * 8;
  constexpr int NT = TN / 32;           // col tiles per wave

  f32x4 acc[4][NT] = {};
  const f16* Ag = A + (size_t)by * 128 * KDIM;
  const f16* Bg = BT + (size_t)bx * TN * KDIM;

  for (int k0 = 0; k0 < KDIM; k0 += 32) {
    __syncthreads();
#pragma unroll
    for (int j = 0; j < 2; ++j) {
      const int r0 = wave * 32 + j * 16;
      async16(Ag + (size_t)(r0 + srow) * KDIM + k0 + scol, &As[r0 * 32]);
    }
#pragma unroll
    for (int j = 0; j < TN / 64; ++j) {
      const int r0 = wave * (TN / 4) + j * 16;
      async16(Bg + (size_t)(r0 + srow) * KDIM + k0 + scol, &Bs[r0 * 32]);
    }
    __syncthreads();
    f16x8 af[4], bf[NT];
#pragma unroll
    for (int t = 0; t < 4; ++t)
      af[t] = *(const f16x8*)&As[(wm * 64 + t * 16 + lrow) * 32 + quad * 8];
#pragma unroll
    for (int t = 0; t < NT; ++t)
      bf[t] = *(const f16x8*)&Bs[(wn * (TN / 2) + t * 16 + lrow) * 32 + quad * 8];
#pragma unroll
    for (int mt = 0; mt < 4; ++mt)
#pragma unroll
      for (int nt = 0; nt < NT; ++nt)
        acc[mt][nt] = __builtin_amdgcn_mfma_f32_16x16x32_f16(af[mt], bf[nt], acc[mt][nt], 0, 0, 0);
  }

  const int b = (by * 128) >> 8;
  const int nbase0 = (by * 128) & 255;
#pragma unroll
  for (int mt = 0; mt < 4; ++mt) {
    const int nb = nbase0 + wm * 64 + mt * 16 + quad * 4;
#pragma unroll
    for (int nt = 0; nt < NT; ++nt) {
      const int gc = bx * TN + wn * (TN / 2) + nt * 16 + lrow;
      f16x4 v;
#pragma unroll
      for (int r = 0; r < 4; ++r) v[r] = (f16)acc[mt][nt][r];
      *(f16x4*)&outT[((size_t)b * NCOLS + gc) * 256 + nb] = v;
    }
  }

  // fused e-dot: per-lane partial over its NT cols, quad-shuffle reduce, atomicAdd
  float a1v[NT], a2v[NT];
#pragma unroll
  for (int nt = 0; nt < NT; ++nt) {
    const int gc = bx * TN + wn * (TN / 2) + nt * 16 + lrow;
    if (EDOT == 1) {
      int hh = gc >> 8, oo = gc & 255;
      a1v[nt] = avec[hh * 512 + oo];
      a2v[nt] = avec[hh * 512 + 256 + oo];
    } else {
      a1v[nt] = avec[gc];
      a2v[nt] = avec[NCOLS + gc];
    }
  }
  const int hblk = (EDOT == 1) ? ((bx * TN) >> 8) : 0;
  const int ebase = (EDOT == 1) ? ((b * 8 + hblk) * 256) : (b * 256);
#pragma unroll
  for (int mt = 0; mt < 4; ++mt) {
    float s1[4] = {0.f, 0.f, 0.f, 0.f}, s2[4] = {0.f, 0.f, 0.f, 0.f};
#pragma unroll
    for (int nt = 0; nt < NT; ++nt)
#pragma unroll
      for (int r = 0; r < 4; ++r) {
        s1[r] += acc[mt][nt][r] * a1v[nt];
        s2[r] += acc[mt][nt][r] * a2v[nt];
      }
#pragma unroll
    for (int r = 0; r < 4; ++r)
#pragma unroll
      for (int m = 1; m < 16; m <<= 1) {
        s1[r] += __shfl_xor(s1[r], m);
        s2[r] += __shfl_xor(s2[r], m);
      }
    if (lrow == 0) {
      const int nb = nbase0 + wm * 64 + mt * 16 + quad * 4;
#pragma unroll
      for (int r = 0; r < 4; ++r) {
        atomicAdd(&e1[ebase + nb + r], s1[r]);
        atomicAdd(&e2[ebase + nb + r], s2[r]);
      }
    }
  }
}

#define PSTRIDE 264

// ---------------- fused attention layer 1 ----------------
// grid (h=8, b=32, nt=4): nt-blocks of one (b,h) differ by 256 (mult of 8) -> same XCD.
__global__ __launch_bounds__(256, 4) void k_attn1(
    const f16* __restrict__ WhT, const float* __restrict__ e1g, const float* __restrict__ e2g,
    const int* __restrict__ adj, const float* __restrict__ npm, f16* __restrict__ h1) {
  int h = blockIdx.x, b = blockIdx.y, nt0 = blockIdx.z;
  int bh = b * 8 + h;
  int n0 = nt0 * 64;
  __shared__ f16 P[64 * PSTRIDE];
  int tid = threadIdx.x;
  int wave = tid >> 6, lane = tid & 63;

  // softmax: wave handles rows wave, wave+4, ...; lanes cover m = lane*4..+3
  float4 e2v = *(const float4*)&e2g[bh * 256 + lane * 4];
  float e2m = fmaxf(fmaxf(e2v.x, e2v.y), fmaxf(e2v.z, e2v.w));
#pragma unroll
  for (int m = 1; m < 64; m <<= 1) e2m = fmaxf(e2m, __shfl_xor(e2m, m));
#pragma unroll 4
  for (int i = 0; i < 16; ++i) {
    int row = i * 4 + wave;
    int gn = b * 256 + n0 + row;
    float er = e1g[bh * 256 + n0 + row];
    float sh = er + e2m;
    sh = sh > 0.f ? sh : 0.2f * sh;     // upper bound of row max
    int4 aj = *(const int4*)&adj[(size_t)gn * 256 + lane * 4];
    float p0, p1, p2, p3;
    {
      float v = er + e2v.x; v = v > 0.f ? v : 0.2f * v;
      p0 = aj.x ? __expf(v - sh) : 0.f;
      v = er + e2v.y; v = v > 0.f ? v : 0.2f * v;
      p1 = aj.y ? __expf(v - sh) : 0.f;
      v = er + e2v.z; v = v > 0.f ? v : 0.2f * v;
      p2 = aj.z ? __expf(v - sh) : 0.f;
      v = er + e2v.w; v = v > 0.f ? v : 0.2f * v;
      p3 = aj.w ? __expf(v - sh) : 0.f;
    }
    float sm = p0 + p1 + p2 + p3;
#pragma unroll
    for (int m = 1; m < 64; m <<= 1) sm += __shfl_xor(sm, m);
    float rs = 1.f / sm;                // normalize P here
    f16x4 pw;
    pw[0] = (f16)(p0 * rs); pw[1] = (f16)(p1 * rs);
    pw[2] = (f16)(p2 * rs); pw[3] = (f16)(p3 * rs);
    *(f16x4*)&P[row * PSTRIDE + lane * 4] = pw;
  }
  __syncthreads();

  // PV: D[o][n]; A=Wh[o][m] from global (L2-hot), B=P[n][m] from LDS
  int lrow = lane & 15, quad = lane >> 4;
  f32x4 acc[4][4] = {};
  const f16* Ag = WhT + (size_t)bh * 65536;
#pragma unroll 2
  for (int k0 = 0; k0 < 256; k0 += 32) {
    f16x8 af[4], bf[4];
#pragma unroll
    for (int mt = 0; mt < 4; ++mt)
      af[mt] = *(const f16x8*)&Ag[(size_t)(wave * 64 + mt * 16 + lrow) * 256 + k0 + quad * 8];
#pragma unroll
    for (int nt = 0; nt < 4; ++nt)
      bf[nt] = *(const f16x8*)&P[(nt * 16 + lrow) * PSTRIDE + k0 + quad * 8];
#pragma unroll
    for (int mt = 0; mt < 4; ++mt)
#pragma unroll
      for (int nt = 0; nt < 4; ++nt)
        acc[mt][nt] = __builtin_amdgcn_mfma_f32_16x16x32_f16(af[mt], bf[nt], acc[mt][nt], 0, 0, 0);
  }
  // epilogue: lane holds 4 consecutive o (rows), col n = nt*16+lrow
#pragma unroll
  for (int nt = 0; nt < 4; ++nt) {
    int nloc = nt * 16 + lrow;
    int gn = b * 256 + n0 + nloc;
    float pm = npm[gn];
#pragma unroll
    for (int mt = 0; mt < 4; ++mt) {
      int o0 = wave * 64 + mt * 16 + quad * 4;
      f16x4 st;
#pragma unroll
      for (int r = 0; r < 4; ++r) {
        float v = acc[mt][nt][r];
        v = v > 0.f ? v : (__expf(v) - 1.f);
        st[r] = (f16)(v * pm);
      }
      *(f16x4*)&h1[(size_t)gn * 2048 + h * 256 + o0] = st;
    }
  }
}

// ---------------- fused attention layer 2 ----------------
// grid (oh=2, b=32, nt=4)
__global__ __launch_bounds__(256, 4) void k_attn2(
    const f16* __restrict__ Wh2T, const float* __restrict__ e1g, const float* __restrict__ e2g,
    const int* __restrict__ adj, const float* __restrict__ npm, float* __restrict__ out) {
  int oh = blockIdx.x, b = blockIdx.y, nt0 = blockIdx.z;
  int n0 = nt0 * 64;
  __shared__ f16 P[64 * PSTRIDE];
  int tid = threadIdx.x;
  int wave = tid >> 6, lane = tid & 63;

  float4 e2v = *(const float4*)&e2g[b * 256 + lane * 4];
  float e2m = fmaxf(fmaxf(e2v.x, e2v.y), fmaxf(e2v.z, e2v.w));
#pragma unroll
  for (int m = 1; m < 64; m <<= 1) e2m = fmaxf(e2m, __shfl_xor(e2m, m));
#pragma unroll 4
  for (int i = 0; i < 16; ++i) {
    int row = i * 4 + wave;
    int gn = b * 256 + n0 + row;
    float er = e1g[b * 256 + n0 + row];
    float sh = er + e2m;
    sh = sh > 0.f ? sh : 0.2f * sh;
    int4 aj = *(const int4*)&adj[(size_t)gn * 256 + lane * 4];
    float p0, p1, p2, p3;
    {
      float v = er + e2v.x; v = v > 0.f ? v : 0.2f * v;
      p0 = aj.x ? __expf(v - sh) : 0.f;
      v = er + e2v.y; v = v > 0.f ? v : 0.2f * v;
      p1 = aj.y ? __expf(v - sh) : 0.f;
      v = er + e2v.z; v = v > 0.f ? v : 0.2f * v;
      p2 = aj.z ? __expf(v - sh) : 0.f;
      v = er + e2v.w; v = v > 0.f ? v : 0.2f * v;
      p3 = aj.w ? __expf(v - sh) : 0.f;
    }
    float sm = p0 + p1 + p2 + p3;
#pragma unroll
    for (int m = 1; m < 64; m <<= 1) sm += __shfl_xor(sm, m);
    float rs = 1.f / sm;
    f16x4 pw;
    pw[0] = (f16)(p0 * rs); pw[1] = (f16)(p1 * rs);
    pw[2] = (f16)(p2 * rs); pw[3] = (f16)(p3 * rs);
    *(f16x4*)&P[row * PSTRIDE + lane * 4] = pw;
  }
  __syncthreads();

  int lrow = lane & 15, quad = lane >> 4;
  f32x4 acc[4][4] = {};
  const f16* Ag = Wh2T + (size_t)b * 512 * 256 + (size_t)oh * 65536;
#pragma unroll 2
  for (int k0 = 0; k0 < 256; k0 += 32) {
    f16x8 af[4], bf[4];
#pragma unroll
    for (int mt = 0; mt < 4; ++mt)
      af[mt] = *(const f16x8*)&Ag[(size_t)(wave * 64 + mt * 16 + lrow) * 256 + k0 + quad * 8];
#pragma unroll
    for (int nt = 0; nt < 4; ++nt)
      bf[nt] = *(const f16x8*)&P[(nt * 16 + lrow) * PSTRIDE + k0 + quad * 8];
#pragma unroll
    for (int mt = 0; mt < 4; ++mt)
#pragma unroll
      for (int nt = 0; nt < 4; ++nt)
        acc[mt][nt] = __builtin_amdgcn_mfma_f32_16x16x32_f16(af[mt], bf[nt], acc[mt][nt], 0, 0, 0);
  }
#pragma unroll
  for (int nt = 0; nt < 4; ++nt) {
    int nloc = nt * 16 + lrow;
    int gn = b * 256 + n0 + nloc;
    float pm = npm[gn];
#pragma unroll
    for (int mt = 0; mt < 4; ++mt) {
      int o0 = oh * 256 + wave * 64 + mt * 16 + quad * 4;
      float4 st;
      float v0 = acc[mt][nt][0] * pm;
      float v1 = acc[mt][nt][1] * pm;
      float v2 = acc[mt][nt][2] * pm;
      float v3 = acc[mt][nt][3] * pm;
      st.x = v0 > 0.f ? v0 : (__expf(v0) - 1.f);
      st.y = v1 > 0.f ? v1 : (__expf(v1) - 1.f);
      st.z = v2 > 0.f ? v2 : (__expf(v2) - 1.f);
      st.w = v3 > 0.f ? v3 : (__expf(v3) - 1.f);
      *(float4*)&out[(size_t)gn * 512 + o0] = st;
    }
  }
}

extern "C" void kernel_launch(void* const* d_in, const int* in_sizes, int n_in,
                              void* d_out, int out_size, void* d_ws, size_t ws_size,
                              hipStream_t stream) {
  (void)in_sizes; (void)n_in; (void)out_size; (void)ws_size;
  const int*   fea   = (const int*)d_in[0];
  const int*   adj   = (const int*)d_in[1];
  const float* npm   = (const float*)d_in[2];
  const float* embed = (const float*)d_in[3];
  const float* Whd   = (const float*)d_in[4];
  const float* ah    = (const float*)d_in[5];
  const float* Wo    = (const float*)d_in[6];
  const float* ao    = (const float*)d_in[7];
  float* out = (float*)d_out;

  char* ws = (char*)d_ws;
  f16* x16  = (f16*)ws;  ws += (size_t)8192 * 320 * 2;
  f16* WcT  = (f16*)ws;  ws += (size_t)2048 * 320 * 2;
  f16* WoT  = (f16*)ws;  ws += (size_t)512 * 2048 * 2;
  f16* WhT  = (f16*)ws;  ws += (size_t)32 * 8 * 256 * 256 * 2;   // [b][h*256+o][n]
  f16* h1   = (f16*)ws;  ws += (size_t)8192 * 2048 * 2;          // [bn][h*256+o]
  f16* Wh2T = (f16*)ws;  ws += (size_t)32 * 512 * 256 * 2;       // [b][o2][n]
  float* e1  = (float*)ws; ws += (size_t)65536 * 4;
  float* e2  = (float*)ws; ws += (size_t)65536 * 4;
  float* e12 = (float*)ws; ws += (size_t)8192 * 4;
  float* e22 = (float*)ws; ws += (size_t)8192 * 4;

  // zero the atomic e-accumulators (e1,e2,e12,e22 are contiguous)
  hipMemsetAsync(e1, 0, ((size_t)65536 * 2 + 8192 * 2) * 4, stream);

  k_prep_x<<<8192, 320, 0, stream>>>(fea, embed, x16);
  k_prep_wc<<<dim3(10, 8, 8), 256, 0, stream>>>(Whd, WcT);
  k_prep_wo<<<dim3(64, 16), 256, 0, stream>>>(Wo, WoT);

  // swizzled grids: A-row-tile fastest (blockIdx.x)
  k_gemm<320, 2048, 128, 1><<<dim3(64, 16), 256, 0, stream>>>(x16, WcT, WhT, ah, e1, e2);
  k_attn1<<<dim3(8, 32, 4), 256, 0, stream>>>(WhT, e1, e2, adj, npm, h1);

  k_gemm<2048, 512, 64, 2><<<dim3(64, 8), 256, 0, stream>>>(h1, WoT, Wh2T, ao, e12, e22);
  k_attn2<<<dim3(2, 32, 4), 256, 0, stream>>>(Wh2T, e12, e22, adj, npm, out);
}